// Round 1
// baseline (279.199 us; speedup 1.0000x reference)
//
#include <hip/hip_runtime.h>
#include <math.h>

#define NN   256
#define DZv  256
#define LL   256
#define HH   512
#define MLPHv 2048
#define INCv 8
#define NCOLS 150   // 4 + 16 + 128 + 2 fused head columns

// ---------------------------------------------------------------------------
// Fused head weights: Mf[c, k] = sum_h conv_w[h,c] * W_head[h,k]
//                     beta[k]  = sum_h conv_b[h]  * W_head[h,k] + b_head[k]
// Column layout k: [cat0: 0..3][cat1: 4..19][cat2: 20..147][num: 148..149]
// ---------------------------------------------------------------------------
__global__ __launch_bounds__(256) void fuse_heads_kernel(
    const float* __restrict__ conv_w, const float* __restrict__ conv_b,
    const float* __restrict__ cw0, const float* __restrict__ cb0,
    const float* __restrict__ cw1, const float* __restrict__ cb1,
    const float* __restrict__ cw2, const float* __restrict__ cb2,
    const float* __restrict__ nw,  const float* __restrict__ nb,
    float* __restrict__ Mf, float* __restrict__ beta)
{
    int k = blockIdx.x;
    const float* W; const float* B; int off, card;
    if (k < 4)        { W = cw0; B = cb0; off = 0;   card = 4;   }
    else if (k < 20)  { W = cw1; B = cb1; off = 4;   card = 16;  }
    else if (k < 148) { W = cw2; B = cb2; off = 20;  card = 128; }
    else              { W = nw;  B = nb;  off = 148; card = 2;   }
    int kc  = k - off;
    int tid = threadIdx.x;
    float part[INCv + 1];
#pragma unroll
    for (int c = 0; c <= INCv; ++c) part[c] = 0.f;
    for (int h = tid; h < HH; h += 256) {
        float wv = W[h * card + kc];
#pragma unroll
        for (int c = 0; c < INCv; ++c) part[c] += conv_w[h * INCv + c] * wv;
        part[INCv] += conv_b[h] * wv;
    }
    __shared__ float red[256];
    for (int c = 0; c <= INCv; ++c) {
        red[tid] = part[c];
        __syncthreads();
        for (int s2 = 128; s2 > 0; s2 >>= 1) {
            if (tid < s2) red[tid] += red[tid + s2];
            __syncthreads();
        }
        if (tid == 0) {
            if (c < INCv) Mf[c * NCOLS + k] = red[0];
            else          beta[k] = red[0] + B[kc];
        }
        __syncthreads();
    }
}

// ---------------------------------------------------------------------------
// fp32 GEMM: C[256 x 2048] = act(A[256 x K] @ W[K x 2048] + bias)
// 64x64 tile, BK=16, 256 threads, 4x4 micro-tile. RELU applied on store.
// ---------------------------------------------------------------------------
template <bool RELU>
__global__ __launch_bounds__(256) void gemm_k(
    const float* __restrict__ A, const float* __restrict__ W,
    const float* __restrict__ bias, float* __restrict__ C, int K)
{
    __shared__ float As[16][68];   // [k][m], pad 68 keeps float4 alignment, rotates banks
    __shared__ float Bs[16][68];   // [k][n]
    const int bm  = blockIdx.x * 64;
    const int bn  = blockIdx.y * 64;
    const int tid = threadIdx.x;
    const int ty = tid >> 4, tx = tid & 15;
    const int arow = tid >> 2, acol = (tid & 3) << 2;   // A tile 64x16
    const int brow = tid >> 4, bcol = (tid & 15) << 2;  // B tile 16x64
    float acc[4][4] = {};
    for (int k0 = 0; k0 < K; k0 += 16) {
        float4 a = *(const float4*)&A[(bm + arow) * K + k0 + acol];
        float4 b = *(const float4*)&W[(size_t)(k0 + brow) * 2048 + bn + bcol];
        As[acol + 0][arow] = a.x;
        As[acol + 1][arow] = a.y;
        As[acol + 2][arow] = a.z;
        As[acol + 3][arow] = a.w;
        *(float4*)&Bs[brow][bcol] = b;
        __syncthreads();
#pragma unroll
        for (int k = 0; k < 16; ++k) {
            float4 av = *(const float4*)&As[k][ty << 2];
            float4 bv = *(const float4*)&Bs[k][tx << 2];
            float aa[4] = {av.x, av.y, av.z, av.w};
            float bb[4] = {bv.x, bv.y, bv.z, bv.w};
#pragma unroll
            for (int i = 0; i < 4; ++i)
#pragma unroll
                for (int j = 0; j < 4; ++j)
                    acc[i][j] = fmaf(aa[i], bb[j], acc[i][j]);
        }
        __syncthreads();
    }
    float4 bv = *(const float4*)&bias[bn + (tx << 2)];
    float bb[4] = {bv.x, bv.y, bv.z, bv.w};
#pragma unroll
    for (int i = 0; i < 4; ++i) {
        float4 v;
        v.x = acc[i][0] + bb[0];
        v.y = acc[i][1] + bb[1];
        v.z = acc[i][2] + bb[2];
        v.w = acc[i][3] + bb[3];
        if (RELU) {
            v.x = fmaxf(v.x, 0.f); v.y = fmaxf(v.y, 0.f);
            v.z = fmaxf(v.z, 0.f); v.w = fmaxf(v.w, 0.f);
        }
        *(float4*)&C[(size_t)(bm + (ty << 2) + i) * 2048 + bn + (tx << 2)] = v;
    }
}

// ---------------------------------------------------------------------------
// Cat heads: grid (32, 3) x 256 threads. blockIdx.y = group g.
// One thread per (n, j): l = 2*(g*32+j). Two-pass (max/arg, then lse) to
// avoid a 128-float scratch array.
// ---------------------------------------------------------------------------
__global__ __launch_bounds__(256) void cat_kernel(
    const float* __restrict__ rh, const float* __restrict__ Mf,
    const float* __restrict__ beta, const int* __restrict__ cat_target,
    float* __restrict__ out)
{
    const int g = blockIdx.y;
    const int card = (g == 0) ? 4 : (g == 1) ? 16 : 128;
    const int off  = (g == 0) ? 0 : (g == 1) ? 4  : 20;
    __shared__ float Ms[INCv][128];
    __shared__ float Bsh[128];
    const int tid = threadIdx.x;
    for (int i = tid; i < card * INCv; i += 256) {
        int c = i / card, k = i % card;
        Ms[c][k] = Mf[c * NCOLS + off + k];
    }
    for (int i = tid; i < card; i += 256) Bsh[i] = beta[off + i];
    __syncthreads();

    const int idx = blockIdx.x * 256 + tid;   // 0..8191
    const int n = idx >> 5, j = idx & 31;
    const int ci = g * 32 + j;
    const int l  = ci * 2;
    float rv[INCv];
#pragma unroll
    for (int c = 0; c < INCv; ++c) rv[c] = rh[n * MLPHv + c * LL + l];

    float mx = -1e30f; int arg = 0;
    for (int k = 0; k < card; ++k) {
        float s = Bsh[k];
#pragma unroll
        for (int c = 0; c < INCv; ++c) s += rv[c] * Ms[c][k];
        if (s > mx) { mx = s; arg = k; }
    }
    const int tg = cat_target[n * 96 + ci];
    float sum = 0.f, stg = 0.f;
    for (int k = 0; k < card; ++k) {
        float s = Bsh[k];
#pragma unroll
        for (int c = 0; c < INCv; ++c) s += rv[c] * Ms[c][k];
        sum += expf(s - mx);
        if (k == tg) stg = s;
    }
    float lse = mx + logf(sum);
    out[NN * LL * 3 + n * 96 + ci] = lse - stg;
    float* u = out + (size_t)(n * LL + l) * 3;
    u[0] = (float)arg; u[1] = 0.f; u[2] = 0.f;
}

// ---------------------------------------------------------------------------
// Num head: 160 blocks x 256 threads, one thread per (n, ni).
// NUM_IDX order: odds 1..191 (ni 0..95), then 192..255 (ni 96..159).
// ---------------------------------------------------------------------------
__global__ __launch_bounds__(256) void num_kernel(
    const float* __restrict__ rh, const float* __restrict__ Mf,
    const float* __restrict__ beta, const float* __restrict__ num_target,
    float* __restrict__ out)
{
    const int idx = blockIdx.x * 256 + threadIdx.x;  // 0..40959
    const int n = idx / 160, ni = idx % 160;
    const int l = (ni < 96) ? (2 * ni + 1) : (96 + ni);
    float rv[INCv];
#pragma unroll
    for (int c = 0; c < INCv; ++c) rv[c] = rh[n * MLPHv + c * LL + l];
    float p0 = beta[148], p1 = beta[149];
#pragma unroll
    for (int c = 0; c < INCv; ++c) {
        p0 += rv[c] * Mf[c * NCOLS + 148];
        p1 += rv[c] * Mf[c * NCOLS + 149];
    }
    float mu = 1.f / (1.f + expf(-p0));
    float sp = (p1 > 20.f) ? p1 : log1pf(expf(p1));
    float s  = sp + 1e-4f;
    const float hb = 1.f / 198.f;
    float t  = num_target[n * 160 + ni];
    float cp = 1.f / (1.f + expf(-((t + hb - mu) / s)));
    float cm = 1.f / (1.f + expf(-((t - hb - mu) / s)));
    float prob = (t < hb) ? cp : ((t > 1.f - hb) ? (1.f - cm) : (cp - cm));
    out[NN * LL * 3 + NN * 96 + n * 160 + ni] = -logf(fmaxf(prob, 1e-7f));
    float* u = out + (size_t)(n * LL + l) * 3;
    u[0] = 0.f; u[1] = rintf(mu * 99.f) / 99.f; u[2] = 0.f;
}

// ---------------------------------------------------------------------------
extern "C" void kernel_launch(void* const* d_in, const int* in_sizes, int n_in,
                              void* d_out, int out_size, void* d_ws, size_t ws_size,
                              hipStream_t stream)
{
    const float* z   = (const float*)d_in[0];
    const float* w0  = (const float*)d_in[1];
    const float* b0  = (const float*)d_in[2];
    const float* w1  = (const float*)d_in[3];
    const float* b1  = (const float*)d_in[4];
    const float* w2  = (const float*)d_in[5];
    const float* b2  = (const float*)d_in[6];
    const float* cvw = (const float*)d_in[7];
    const float* cvb = (const float*)d_in[8];
    const float* cw0 = (const float*)d_in[9];
    const float* cb0 = (const float*)d_in[10];
    const float* cw1 = (const float*)d_in[11];
    const float* cb1 = (const float*)d_in[12];
    const float* cw2 = (const float*)d_in[13];
    const float* cb2 = (const float*)d_in[14];
    const float* nw  = (const float*)d_in[15];
    const float* nb  = (const float*)d_in[16];
    const float* num_target = (const float*)d_in[17];
    const int*   cat_target = (const int*)d_in[18];
    float* out = (float*)d_out;
    float* ws  = (float*)d_ws;

    float* h0   = ws;                 // 256*2048
    float* h1   = ws + 524288;        // 256*2048
    float* rh2  = ws + 1048576;       // 256*2048 (stores relu(h2))
    float* Mf   = ws + 1572864;       // 8*150
    float* beta = Mf + 8 * NCOLS;     // 150

    fuse_heads_kernel<<<dim3(NCOLS), 256, 0, stream>>>(
        cvw, cvb, cw0, cb0, cw1, cb1, cw2, cb2, nw, nb, Mf, beta);

    gemm_k<true><<<dim3(4, 32), 256, 0, stream>>>(z,  w0, b0, h0,  256);
    gemm_k<true><<<dim3(4, 32), 256, 0, stream>>>(h0, w1, b1, h1,  2048);
    gemm_k<true><<<dim3(4, 32), 256, 0, stream>>>(h1, w2, b2, rh2, 2048);

    cat_kernel<<<dim3(32, 3), 256, 0, stream>>>(rh2, Mf, beta, cat_target, out);
    num_kernel<<<dim3(160),   256, 0, stream>>>(rh2, Mf, beta, num_target, out);
}

// Round 4
// 83.581 us; speedup vs baseline: 3.3405x; 3.3405x over previous
//
#include <hip/hip_runtime.h>
#include <hip/hip_fp16.h>
#include <math.h>

#define NN   256
#define LL   256
#define HH   512
#define MLPHv 2048
#define INCv 8
#define NCOLS 150   // 4 + 16 + 128 + 2 fused head columns

typedef _Float16 f16x8 __attribute__((ext_vector_type(8)));
typedef float    f32x4 __attribute__((ext_vector_type(4)));

// ---------------------------------------------------------------------------
// fp32 -> fp16 hi/lo split:  a ≈ hi + lo/4096, |residual| <= 2^-22 |a|.
// hi = RN_fp16(a); lo = RN_fp16((a-hi)*4096) -- scaling keeps lo in the
// fp16 normal range for all relevant magnitudes.
// ---------------------------------------------------------------------------
__device__ __forceinline__ void pack8(const float* fv, uint4& hv, uint4& lv)
{
    unsigned short h[8], l[8];
#pragma unroll
    for (int j = 0; j < 8; ++j) {
        __half hh = __float2half_rn(fv[j]);
        h[j] = __half_as_ushort(hh);
        float rem = fv[j] - __half2float(hh);
        l[j] = __half_as_ushort(__float2half_rn(rem * 4096.f));
    }
    hv.x = (unsigned)h[0] | ((unsigned)h[1] << 16);
    hv.y = (unsigned)h[2] | ((unsigned)h[3] << 16);
    hv.z = (unsigned)h[4] | ((unsigned)h[5] << 16);
    hv.w = (unsigned)h[6] | ((unsigned)h[7] << 16);
    lv.x = (unsigned)l[0] | ((unsigned)l[1] << 16);
    lv.y = (unsigned)l[2] | ((unsigned)l[3] << 16);
    lv.z = (unsigned)l[4] | ((unsigned)l[5] << 16);
    lv.w = (unsigned)l[6] | ((unsigned)l[7] << 16);
}

// ---------------------------------------------------------------------------
// fp16 hi/lo split MFMA GEMM emulating fp32 (24-bit effective):
//   acc = ah*bh + (ah*bl + al*bh)/4096   (3 MFMA, 2 accumulator sets)
// BM=BN=128, BK=64, 512 threads = 8 waves (2x4), 64x32 tile per wave.
// LDS fragment-direct layout [s(2)][grp16(8)][slot64][8 f16]:
// slot l = (row&15) + 16*koct; frag read = b128 at lane*16B, conflict-free.
// DIRECT: fused bias+relu to outp; else fp32 partial at outp+z*524288.
// ---------------------------------------------------------------------------
template <bool DIRECT>
__global__ __launch_bounds__(512, 2) void gemmhl(
    const float* __restrict__ A, const float* __restrict__ W,
    const float* __restrict__ bias, float* __restrict__ outp,
    int K, int kchunk, int nsteps)
{
    __shared__ unsigned short sAh[8192];
    __shared__ unsigned short sAl[8192];
    __shared__ unsigned short sBh[8192];
    __shared__ unsigned short sBl[8192];

    const int tid   = threadIdx.x;
    const int bn    = blockIdx.x * 128;
    const int bm    = blockIdx.y * 128;
    const int kbase = blockIdx.z * kchunk;
    const int lane  = tid & 63;
    const int wv    = tid >> 6, wr = wv >> 2, wc = wv & 3;
    const int rA    = tid >> 2, ktA = (tid & 3) << 4;   // A: row, 16-k strip
    const int nW    = tid & 127, kqW = tid >> 7;        // W: col, 16-k strip

    f32x4 accH[4][2], accC[4][2];
#pragma unroll
    for (int r = 0; r < 4; ++r)
#pragma unroll
        for (int c = 0; c < 2; ++c) {
            accH[r][c] = (f32x4){0.f, 0.f, 0.f, 0.f};
            accC[r][c] = (f32x4){0.f, 0.f, 0.f, 0.f};
        }

    float aReg[16], wReg[16];

    // ---- initial tile load (global -> regs) ----
    {
        const float* pA = &A[(size_t)(bm + rA) * K + kbase + ktA];
#pragma unroll
        for (int q = 0; q < 4; ++q) {
            float4 v = *(const float4*)(pA + q * 4);
            aReg[q * 4 + 0] = v.x; aReg[q * 4 + 1] = v.y;
            aReg[q * 4 + 2] = v.z; aReg[q * 4 + 3] = v.w;
        }
#pragma unroll
        for (int j = 0; j < 16; ++j)
            wReg[j] = W[(size_t)(kbase + kqW * 16 + j) * 2048 + bn + nW];
    }

    for (int t = 0; t < nsteps; ++t) {
        // ---- convert + write tile t into LDS ----
#pragma unroll
        for (int o2 = 0; o2 < 2; ++o2) {
            uint4 hv, lv;
            pack8(&aReg[o2 * 8], hv, lv);
            const int oo   = ((tid & 3) << 1) + o2;      // k-octet 0..7
            const int base = ((oo >> 2) << 12) + ((rA >> 4) << 9)
                           + (((rA & 15) + ((oo & 3) << 4)) << 3);
            *(uint4*)&sAh[base] = hv;
            *(uint4*)&sAl[base] = lv;
        }
#pragma unroll
        for (int o2 = 0; o2 < 2; ++o2) {
            uint4 hv, lv;
            pack8(&wReg[o2 * 8], hv, lv);
            const int oo   = (kqW << 1) + o2;
            const int base = ((oo >> 2) << 12) + ((nW >> 4) << 9)
                           + (((nW & 15) + ((oo & 3) << 4)) << 3);
            *(uint4*)&sBh[base] = hv;
            *(uint4*)&sBl[base] = lv;
        }

        // ---- prefetch tile t+1 into regs (overlaps MFMA below) ----
        if (t + 1 < nsteps) {
            const int kb = kbase + (t + 1) * 64;
            const float* pA = &A[(size_t)(bm + rA) * K + kb + ktA];
#pragma unroll
            for (int q = 0; q < 4; ++q) {
                float4 v = *(const float4*)(pA + q * 4);
                aReg[q * 4 + 0] = v.x; aReg[q * 4 + 1] = v.y;
                aReg[q * 4 + 2] = v.z; aReg[q * 4 + 3] = v.w;
            }
#pragma unroll
            for (int j = 0; j < 16; ++j)
                wReg[j] = W[(size_t)(kb + kqW * 16 + j) * 2048 + bn + nW];
        }

        __syncthreads();

        // ---- MFMA over the two K32 halves of this BK=64 tile ----
#pragma unroll
        for (int s = 0; s < 2; ++s) {
            f16x8 aH[4], aL[4], bH[2], bL[2];
#pragma unroll
            for (int r = 0; r < 4; ++r) {
                const int off = (s << 12) + (((wr << 2) + r) << 9) + (lane << 3);
                aH[r] = *(const f16x8*)&sAh[off];
                aL[r] = *(const f16x8*)&sAl[off];
            }
#pragma unroll
            for (int c = 0; c < 2; ++c) {
                const int off = (s << 12) + (((wc << 1) + c) << 9) + (lane << 3);
                bH[c] = *(const f16x8*)&sBh[off];
                bL[c] = *(const f16x8*)&sBl[off];
            }
#pragma unroll
            for (int r = 0; r < 4; ++r)
#pragma unroll
                for (int c = 0; c < 2; ++c) {
                    accH[r][c] = __builtin_amdgcn_mfma_f32_16x16x32_f16(aH[r], bH[c], accH[r][c], 0, 0, 0);
                    accC[r][c] = __builtin_amdgcn_mfma_f32_16x16x32_f16(aH[r], bL[c], accC[r][c], 0, 0, 0);
                    accC[r][c] = __builtin_amdgcn_mfma_f32_16x16x32_f16(aL[r], bH[c], accC[r][c], 0, 0, 0);
                }
        }
        __syncthreads();
    }

    // ---- epilogue: combine scaled accumulators ----
    const float inv = 1.f / 4096.f;
    float* pout = DIRECT ? outp : (outp + (size_t)blockIdx.z * 524288);
#pragma unroll
    for (int r = 0; r < 4; ++r)
#pragma unroll
        for (int c = 0; c < 2; ++c) {
            const int row = bm + wr * 64 + r * 16 + ((lane >> 4) << 2);
            const int col = bn + wc * 32 + c * 16 + (lane & 15);
            const float vb = DIRECT ? bias[col] : 0.f;
#pragma unroll
            for (int e = 0; e < 4; ++e) {
                float v = accH[r][c][e] + accC[r][c][e] * inv;
                if (DIRECT) v = fmaxf(v + vb, 0.f);
                pout[(size_t)(row + e) * 2048 + col] = v;
            }
        }
}

// ---------------------------------------------------------------------------
// Reduce ksplit partials + bias + relu -> fp32 out.
// ---------------------------------------------------------------------------
__global__ __launch_bounds__(256) void reduce_bias_relu(
    const float* __restrict__ part, const float* __restrict__ bias,
    float* __restrict__ out, int ksplit)
{
    const int r  = blockIdx.x;        // 512 blocks
    const int ct = r & 15, rg = r >> 4;
    const int e  = threadIdx.x * 4;
    const int row = rg * 8 + (e >> 7);
    const int col = ct * 128 + (e & 127);
    const size_t idx = (size_t)row * 2048 + col;
    float4 s = *(const float4*)&bias[col];
    for (int k = 0; k < ksplit; ++k) {
        const float4 p = *(const float4*)&part[(size_t)k * 524288 + idx];
        s.x += p.x; s.y += p.y; s.z += p.z; s.w += p.w;
    }
    s.x = fmaxf(s.x, 0.f); s.y = fmaxf(s.y, 0.f);
    s.z = fmaxf(s.z, 0.f); s.w = fmaxf(s.w, 0.f);
    *(float4*)&out[idx] = s;
}

// ---------------------------------------------------------------------------
// Fused head weights: Mf[c,k] = sum_h conv_w[h,c]*W_head[h,k];
// beta[k] = sum_h conv_b[h]*W_head[h,k] + b_head[k]
// ---------------------------------------------------------------------------
__global__ __launch_bounds__(256) void fuse_heads_kernel(
    const float* __restrict__ conv_w, const float* __restrict__ conv_b,
    const float* __restrict__ cw0, const float* __restrict__ cb0,
    const float* __restrict__ cw1, const float* __restrict__ cb1,
    const float* __restrict__ cw2, const float* __restrict__ cb2,
    const float* __restrict__ nw,  const float* __restrict__ nb,
    float* __restrict__ Mf, float* __restrict__ beta)
{
    int k = blockIdx.x;
    const float* W; const float* B; int off, card;
    if (k < 4)        { W = cw0; B = cb0; off = 0;   card = 4;   }
    else if (k < 20)  { W = cw1; B = cb1; off = 4;   card = 16;  }
    else if (k < 148) { W = cw2; B = cb2; off = 20;  card = 128; }
    else              { W = nw;  B = nb;  off = 148; card = 2;   }
    int kc  = k - off;
    int tid = threadIdx.x;
    float part[INCv + 1];
#pragma unroll
    for (int c = 0; c <= INCv; ++c) part[c] = 0.f;
    for (int h = tid; h < HH; h += 256) {
        float wv = W[h * card + kc];
#pragma unroll
        for (int c = 0; c < INCv; ++c) part[c] += conv_w[h * INCv + c] * wv;
        part[INCv] += conv_b[h] * wv;
    }
    __shared__ float red[256];
    for (int c = 0; c <= INCv; ++c) {
        red[tid] = part[c];
        __syncthreads();
        for (int s2 = 128; s2 > 0; s2 >>= 1) {
            if (tid < s2) red[tid] += red[tid + s2];
            __syncthreads();
        }
        if (tid == 0) {
            if (c < INCv) Mf[c * NCOLS + k] = red[0];
            else          beta[k] = red[0] + B[kc];
        }
        __syncthreads();
    }
}

// ---------------------------------------------------------------------------
// Cat heads: grid (32,3) x 256. One thread per (n, j), l = 2*(g*32+j).
// ---------------------------------------------------------------------------
__global__ __launch_bounds__(256) void cat_kernel(
    const float* __restrict__ rh, const float* __restrict__ Mf,
    const float* __restrict__ beta, const int* __restrict__ cat_target,
    float* __restrict__ out)
{
    const int g = blockIdx.y;
    const int card = (g == 0) ? 4 : (g == 1) ? 16 : 128;
    const int off  = (g == 0) ? 0 : (g == 1) ? 4  : 20;
    __shared__ float Ms[INCv][128];
    __shared__ float Bsh[128];
    const int tid = threadIdx.x;
    for (int i = tid; i < card * INCv; i += 256) {
        int c = i / card, k = i % card;
        Ms[c][k] = Mf[c * NCOLS + off + k];
    }
    for (int i = tid; i < card; i += 256) Bsh[i] = beta[off + i];
    __syncthreads();

    const int idx = blockIdx.x * 256 + tid;
    const int n = idx >> 5, j = idx & 31;
    const int ci = g * 32 + j;
    const int l  = ci * 2;
    float rv[INCv];
#pragma unroll
    for (int c = 0; c < INCv; ++c) rv[c] = rh[n * MLPHv + c * LL + l];

    float mx = -1e30f; int arg = 0;
    for (int k = 0; k < card; ++k) {
        float s = Bsh[k];
#pragma unroll
        for (int c = 0; c < INCv; ++c) s += rv[c] * Ms[c][k];
        if (s > mx) { mx = s; arg = k; }
    }
    const int tg = cat_target[n * 96 + ci];
    float sum = 0.f, stg = 0.f;
    for (int k = 0; k < card; ++k) {
        float s = Bsh[k];
#pragma unroll
        for (int c = 0; c < INCv; ++c) s += rv[c] * Ms[c][k];
        sum += expf(s - mx);
        if (k == tg) stg = s;
    }
    float lse = mx + logf(sum);
    out[NN * LL * 3 + n * 96 + ci] = lse - stg;
    float* u = out + (size_t)(n * LL + l) * 3;
    u[0] = (float)arg; u[1] = 0.f; u[2] = 0.f;
}

// ---------------------------------------------------------------------------
// Num head: one thread per (n, ni).
// ---------------------------------------------------------------------------
__global__ __launch_bounds__(256) void num_kernel(
    const float* __restrict__ rh, const float* __restrict__ Mf,
    const float* __restrict__ beta, const float* __restrict__ num_target,
    float* __restrict__ out)
{
    const int idx = blockIdx.x * 256 + threadIdx.x;  // 0..40959
    const int n = idx / 160, ni = idx % 160;
    const int l = (ni < 96) ? (2 * ni + 1) : (96 + ni);
    float rv[INCv];
#pragma unroll
    for (int c = 0; c < INCv; ++c) rv[c] = rh[n * MLPHv + c * LL + l];
    float p0 = beta[148], p1 = beta[149];
#pragma unroll
    for (int c = 0; c < INCv; ++c) {
        p0 += rv[c] * Mf[c * NCOLS + 148];
        p1 += rv[c] * Mf[c * NCOLS + 149];
    }
    float mu = 1.f / (1.f + expf(-p0));
    float sp = (p1 > 20.f) ? p1 : log1pf(expf(p1));
    float s  = sp + 1e-4f;
    const float hb = 1.f / 198.f;
    float t  = num_target[n * 160 + ni];
    float cp = 1.f / (1.f + expf(-((t + hb - mu) / s)));
    float cm = 1.f / (1.f + expf(-((t - hb - mu) / s)));
    float prob = (t < hb) ? cp : ((t > 1.f - hb) ? (1.f - cm) : (cp - cm));
    out[NN * LL * 3 + NN * 96 + n * 160 + ni] = -logf(fmaxf(prob, 1e-7f));
    float* u = out + (size_t)(n * LL + l) * 3;
    u[0] = 0.f; u[1] = rintf(mu * 99.f) / 99.f; u[2] = 0.f;
}

// ---------------------------------------------------------------------------
extern "C" void kernel_launch(void* const* d_in, const int* in_sizes, int n_in,
                              void* d_out, int out_size, void* d_ws, size_t ws_size,
                              hipStream_t stream)
{
    const float* z   = (const float*)d_in[0];
    const float* w0  = (const float*)d_in[1];
    const float* b0  = (const float*)d_in[2];
    const float* w1  = (const float*)d_in[3];
    const float* b1  = (const float*)d_in[4];
    const float* w2  = (const float*)d_in[5];
    const float* b2  = (const float*)d_in[6];
    const float* cvw = (const float*)d_in[7];
    const float* cvb = (const float*)d_in[8];
    const float* cw0 = (const float*)d_in[9];
    const float* cb0 = (const float*)d_in[10];
    const float* cw1 = (const float*)d_in[11];
    const float* cb1 = (const float*)d_in[12];
    const float* cw2 = (const float*)d_in[13];
    const float* cb2 = (const float*)d_in[14];
    const float* nw  = (const float*)d_in[15];
    const float* nb  = (const float*)d_in[16];
    const float* num_target = (const float*)d_in[17];
    const int*   cat_target = (const int*)d_in[18];
    float* out = (float*)d_out;
    float* ws  = (float*)d_ws;

    float* rh0  = ws;                      // 524288
    float* rh1  = ws + 524288;
    float* rh2  = ws + 1048576;
    float* Mf   = ws + 1572864;            // 8*150
    float* beta = Mf + 8 * NCOLS;          // 150
    const size_t PART_OFF = 1575936;       // 16B-aligned
    float* part = ws + PART_OFF;
    const size_t avail_f = ws_size / sizeof(float);
    int ksplit = 0;
    if      (PART_OFF + 8ull * 524288 <= avail_f) ksplit = 8;
    else if (PART_OFF + 4ull * 524288 <= avail_f) ksplit = 4;
    else if (PART_OFF + 2ull * 524288 <= avail_f) ksplit = 2;
    else if (PART_OFF + 1ull * 524288 <= avail_f) ksplit = 1;

    fuse_heads_kernel<<<dim3(NCOLS), 256, 0, stream>>>(
        cvw, cvb, cw0, cb0, cw1, cb1, cw2, cb2, nw, nb, Mf, beta);

    if (ksplit > 0) {
        const int ks0 = (ksplit > 4) ? 4 : ksplit;       // layer 0: K=256
        const int kc0 = 256 / ks0;
        gemmhl<false><<<dim3(16, 2, ks0), 512, 0, stream>>>(z, w0, nullptr, part, 256, kc0, kc0 / 64);
        reduce_bias_relu<<<dim3(512), 256, 0, stream>>>(part, b0, rh0, ks0);

        const int kc = 2048 / ksplit;
        gemmhl<false><<<dim3(16, 2, ksplit), 512, 0, stream>>>(rh0, w1, nullptr, part, 2048, kc, kc / 64);
        reduce_bias_relu<<<dim3(512), 256, 0, stream>>>(part, b1, rh1, ksplit);

        gemmhl<false><<<dim3(16, 2, ksplit), 512, 0, stream>>>(rh1, w2, nullptr, part, 2048, kc, kc / 64);
        reduce_bias_relu<<<dim3(512), 256, 0, stream>>>(part, b2, rh2, ksplit);
    } else {
        gemmhl<true><<<dim3(16, 2, 1), 512, 0, stream>>>(z,   w0, b0, rh0, 256,  256,  4);
        gemmhl<true><<<dim3(16, 2, 1), 512, 0, stream>>>(rh0, w1, b1, rh1, 2048, 2048, 32);
        gemmhl<true><<<dim3(16, 2, 1), 512, 0, stream>>>(rh1, w2, b2, rh2, 2048, 2048, 32);
    }

    cat_kernel<<<dim3(32, 3), 256, 0, stream>>>(rh2, Mf, beta, cat_target, out);
    num_kernel<<<dim3(160),   256, 0, stream>>>(rh2, Mf, beta, num_target, out);
}